// Round 21
// baseline (797.906 us; speedup 1.0000x reference)
//
#include <hip/hip_runtime.h>
#include <hip/hip_bf16.h>

typedef __bf16 bf16_t;
typedef __bf16 bf16x4 __attribute__((ext_vector_type(4)));
typedef __bf16 bf16x8 __attribute__((ext_vector_type(8)));
typedef float f32x4 __attribute__((ext_vector_type(4)));
typedef float f32x16 __attribute__((ext_vector_type(16)));

#define HIDDEN 3584
#define NQH 16
#define NKVH 8
#define DH 256
#define SEQ 4096
#define QKV_COLS 8192   // (NQH + 2*NKVH) * DH
#define Q_SIZE 4096     // NQH * DH
#define KV_SIZE 2048    // NKVH * DH
#define WINDOW 2048
#define SCALE_F 0.0625f // 256^-0.5
#define CAP_F 50.0f

__device__ __forceinline__ void gload16(const bf16_t* g, bf16_t* l) {
  __builtin_amdgcn_global_load_lds((__attribute__((address_space(1))) void*)g,
                                   (__attribute__((address_space(3))) void*)l, 16, 0, 0);
}

// ---------------- f32 -> bf16 conversion, all three inputs in one launch ----------------
__global__ __launch_bounds__(256) void cvt_all(const float* __restrict__ hid,
                                               const float* __restrict__ wqkv,
                                               const float* __restrict__ wo,
                                               bf16_t* __restrict__ hb,
                                               bf16_t* __restrict__ qb,
                                               bf16_t* __restrict__ wb) {
  long i = (long)blockIdx.x * 256 + threadIdx.x;
  const float* src;
  bf16_t* dst;
  long off;
  if (i < 1835008)       { src = hid;  dst = hb; off = i; }
  else if (i < 5505024)  { src = wqkv; dst = qb; off = i - 1835008; }
  else                   { src = wo;   dst = wb; off = i - 5505024; }
  const float4* s4 = (const float4*)src;
  float4 a = s4[off * 2];
  float4 b = s4[off * 2 + 1];
  bf16x8 o;
  o[0] = (bf16_t)a.x; o[1] = (bf16_t)a.y; o[2] = (bf16_t)a.z; o[3] = (bf16_t)a.w;
  o[4] = (bf16_t)b.x; o[5] = (bf16_t)b.y; o[6] = (bf16_t)b.z; o[7] = (bf16_t)b.w;
  *(bf16x8*)(dst + off * 8) = o;
}

// ---------------- bf16 GEMM, C[4096,N] = A[4096,K] * B[N,K]^T ----------------
// 256x256 tile, BK=32, 8 waves (2Mx4N), 4-deep LDS pipeline, counted vmcnt,
// single end-of-tile barrier (round-20).
#define TILE(T, WSTR, STAGE)                                                                \
  {                                                                                         \
    char* buf = lds + ((T) & 3) * 32768;                                                    \
    bf16x8 af[8], b0, b1, b2, b3;                                                           \
    _Pragma("unroll")                                                                       \
    for (int i = 0; i < 8; ++i) af[i] = *(const bf16x8*)(buf + aoff + i * 1024);            \
    b0 = *(const bf16x8*)(buf + boff);                                                      \
    b1 = *(const bf16x8*)(buf + boff + 1024);                                               \
    if (STAGE) {                                                                            \
      char* d = lds + (((T) + 3) & 3) * 32768;                                              \
      gload16(sA0 + ((T) + 3) * 32, (bf16_t*)(d + sdst0));                                  \
      gload16(sA1 + ((T) + 3) * 32, (bf16_t*)(d + 8192 + sdst0));                           \
    }                                                                                       \
    __builtin_amdgcn_s_setprio(1);                                                          \
    _Pragma("unroll")                                                                       \
    for (int i = 0; i < 8; ++i) {                                                           \
      acc[i][0] = __builtin_amdgcn_mfma_f32_16x16x32_bf16(af[i], b0, acc[i][0], 0, 0, 0);   \
      acc[i][1] = __builtin_amdgcn_mfma_f32_16x16x32_bf16(af[i], b1, acc[i][1], 0, 0, 0);   \
    }                                                                                       \
    __builtin_amdgcn_s_setprio(0);                                                          \
    b2 = *(const bf16x8*)(buf + boff + 2048);                                               \
    b3 = *(const bf16x8*)(buf + boff + 3072);                                               \
    if (STAGE) {                                                                            \
      char* d = lds + (((T) + 3) & 3) * 32768;                                              \
      gload16(sB0 + ((T) + 3) * 32, (bf16_t*)(d + 16384 + sdst0));                          \
      gload16(sB1 + ((T) + 3) * 32, (bf16_t*)(d + 24576 + sdst0));                          \
    }                                                                                       \
    __builtin_amdgcn_s_setprio(1);                                                          \
    _Pragma("unroll")                                                                       \
    for (int i = 0; i < 8; ++i) {                                                           \
      acc[i][2] = __builtin_amdgcn_mfma_f32_16x16x32_bf16(af[i], b2, acc[i][2], 0, 0, 0);   \
      acc[i][3] = __builtin_amdgcn_mfma_f32_16x16x32_bf16(af[i], b3, acc[i][3], 0, 0, 0);   \
    }                                                                                       \
    __builtin_amdgcn_s_setprio(0);                                                          \
    asm volatile("s_waitcnt vmcnt(" WSTR ")" ::: "memory");                                 \
    __builtin_amdgcn_s_barrier();                                                           \
  }

template <int K, int MODE>
__global__ __launch_bounds__(512, 2) void gemm_bt(const bf16_t* __restrict__ A,
                                                  const bf16_t* __restrict__ B,
                                                  void* __restrict__ Cout,
                                                  bf16_t* __restrict__ vtout, int N) {
  constexpr int NT = K / 32;
  __shared__ char lds[4 * 32768];
  int tid = threadIdx.x;
  int lane = tid & 63, w = tid >> 6;
  int wm = w >> 2, wn = w & 3;
  int r16 = lane & 15, g = lane >> 4;
  int bid = blockIdx.x;
  long bm = (long)((bid & 7) * 2 + ((bid >> 3) & 1)) * 256;
  long bn = (long)(bid >> 4) * 256;
  int ro = r16 >> 1;
  int asl = ((g + ((r16 & 1) << 2)) ^ ro) << 4;
  int aoff = wm * 8192 + ro * 128 + asl;
  int boff = 16384 + wn * 4096 + ro * 128 + asl;
  int slr = lane >> 3;
  int lc = (lane & 7) ^ slr;
  int kc8 = (lc & 3) * 8;
  long mr0 = (long)(w * 8 + slr) * 2 + (lc >> 2);
  long mr1 = mr0 + 128;
  const bf16_t* sA0 = A + (bm + mr0) * K + kc8;
  const bf16_t* sA1 = A + (bm + mr1) * K + kc8;
  const bf16_t* sB0 = B + (bn + mr0) * K + kc8;
  const bf16_t* sB1 = B + (bn + mr1) * K + kc8;
  int sdst0 = w * 1024;
  f32x4 acc[8][4] = {};
#pragma unroll
  for (int u = 0; u < 3; ++u) {
    char* d = lds + u * 32768;
    gload16(sA0 + u * 32, (bf16_t*)(d + sdst0));
    gload16(sA1 + u * 32, (bf16_t*)(d + 8192 + sdst0));
    gload16(sB0 + u * 32, (bf16_t*)(d + 16384 + sdst0));
    gload16(sB1 + u * 32, (bf16_t*)(d + 24576 + sdst0));
  }
  asm volatile("s_waitcnt vmcnt(8)" ::: "memory");
  __builtin_amdgcn_s_barrier();
  int t = 0;
  for (; t < NT - 3; ++t) TILE(t, "8", true);
  TILE(t, "4", false); ++t;
  TILE(t, "0", false); ++t;
  TILE(t, "0", false);
  if (MODE == 1 && bn >= (Q_SIZE + KV_SIZE)) {
    // fused V-transpose: vt[col_v][row], 4 consecutive rows per lane
#pragma unroll
    for (int i = 0; i < 8; ++i) {
      long row = bm + wm * 128 + i * 16 + g * 4;
#pragma unroll
      for (int j = 0; j < 4; ++j) {
        long colv = bn - (Q_SIZE + KV_SIZE) + wn * 64 + j * 16 + r16;
        bf16x4 o;
#pragma unroll
        for (int r = 0; r < 4; ++r) o[r] = (bf16_t)acc[i][j][r];
        *(bf16x4*)&vtout[colv * SEQ + row] = o;
      }
    }
  } else {
#pragma unroll
    for (int i = 0; i < 8; ++i)
#pragma unroll
      for (int j = 0; j < 4; ++j)
#pragma unroll
        for (int r = 0; r < 4; ++r) {
          long row = bm + wm * 128 + i * 16 + g * 4 + r;
          long col = bn + wn * 64 + j * 16 + r16;
          if (MODE == 1) ((bf16_t*)Cout)[row * N + col] = (bf16_t)acc[i][j][r];
          else           ((float*)Cout)[row * N + col]  = acc[i][j][r];
        }
  }
}

// ---------------- RoPE (neox) for K heads only (q roped inside attn) ----------------
__global__ __launch_bounds__(256) void rope_k_kernel(bf16_t* __restrict__ qkv) {
  long idx = (long)blockIdx.x * 256 + threadIdx.x;  // SEQ * 8 * 16 threads
  int i8 = (int)(idx & 15) * 8;
  long rem = idx >> 4;
  int head = (int)(rem & 7);
  int s = (int)(rem >> 3);
  long p1 = (long)s * QKV_COLS + Q_SIZE + head * DH + i8;
  bf16x8 x1 = *(const bf16x8*)&qkv[p1];
  bf16x8 x2 = *(const bf16x8*)&qkv[p1 + 128];
  bf16x8 o1, o2;
#pragma unroll
  for (int j = 0; j < 8; ++j) {
    float inv_freq = exp2f((float)(i8 + j) * -0.10381025296522976f);
    float fr = (float)s * inv_freq;
    float sn, cs;
    sincosf(fr, &sn, &cs);
    float a = (float)x1[j], b = (float)x2[j];
    o1[j] = (bf16_t)(a * cs - b * sn);
    o2[j] = (bf16_t)(b * cs + a * sn);
  }
  *(bf16x8*)&qkv[p1] = o1;
  *(bf16x8*)&qkv[p1 + 128] = o2;
}

// ---------------- flash attention: softcap + sliding window + GQA ----------------
// 32x32x16 MFMA redesign (round-21): block = 128 q x 1 head, 8 waves =
// 4 q-groups (32 q each) x 2 halves (dh = key-half for QK, d-half for PV).
// K/V staging + dbuf + dispatch identical to round-20 champion. Per wave per
// tile: 16 QK MFMA (own 32 keys) + 16 PV MFMA (own 128 d) = 36 ds_read_b128
// (vs 66 with 16x16) -> attacks the LDS-throughput bound. P[32q][64k] per
// q-group (stride 72 pad), shared by the wave pair via lgkmcnt(0)+s_barrier
// (no vmcnt drain -> staging loads stay in flight).
__global__ __launch_bounds__(512, 2) void attn_kernel(const bf16_t* __restrict__ qkv,
                                                      const bf16_t* __restrict__ vt,
                                                      bf16_t* __restrict__ attn_out) {
  __shared__ bf16_t Kb[2][64 * 256];   // 2 x 32 KB
  __shared__ bf16_t Vb[2][256 * 64];   // 2 x 32 KB
  __shared__ bf16_t Pl[4][32 * 72];    // 18 KB, per q-group P (padded rows)
  __shared__ float  Ls[4][2][32];      // lsum exchange
  int tid = threadIdx.x;
  int lane = tid & 63, w = tid >> 6;
  int l31 = lane & 31, hi = lane >> 5;
  int qg = w >> 1, dh = w & 1;
  int bid = blockIdx.x;
  int swz = (bid & 7) * 64 + (bid >> 3);
  int h = swz >> 5;
  int qb0 = swz & 31;
  int qb = (h & 1) ? (31 - qb0) : qb0;  // complementary pairing
  int kvh = h >> 1;
  int qw = qb * 128 + qg * 32;          // wave's q-group base (32 rows)
  // ---- Q fragments: qf[ks] = Q[qw + l31][ks*16 + hi*8 .. +7] ----
  bf16x8 qf[16];
  long qoff = (long)(qw + l31) * QKV_COLS + h * DH + hi * 8;
#pragma unroll
  for (int ks = 0; ks < 16; ++ks) qf[ks] = *(const bf16x8*)&qkv[qoff + ks * 16];
  // ---- Q-rope in-register: d = ks*16+hi*8+j pairs with d+128 (ks+8) ----
#pragma unroll
  for (int ks = 0; ks < 8; ++ks)
#pragma unroll
    for (int j = 0; j < 8; ++j) {
      int d = ks * 16 + hi * 8 + j;
      float inv_freq = exp2f((float)d * -0.10381025296522976f);
      float fr = (float)(qw + l31) * inv_freq;
      float sn, cs;
      sincosf(fr, &sn, &cs);
      float a = (float)qf[ks][j], b2 = (float)qf[ks + 8][j];
      qf[ks][j] = (bf16_t)(a * cs - b2 * sn);
      qf[ks + 8][j] = (bf16_t)(b2 * cs + a * sn);
    }
  f32x16 acc[4] = {};
  float lsum16[16] = {};
  const bf16_t* kg = qkv + Q_SIZE + (long)kvh * DH;
  const bf16_t* vg = vt + (long)kvh * DH * SEQ;
  bf16_t* pw = &Pl[qg][0];
  int lo = qb * 128 - (WINDOW - 1);
  int t0 = lo > 0 ? (lo >> 6) : 0;
  int t1 = qb * 2 + 2;
  int qlo = qw, qhi = qw + 31;

#define ATTN_STAGE(TT)                                                                   \
  {                                                                                      \
    int b_ = (TT) & 1;                                                                   \
    int kb_ = (TT) * 64;                                                                 \
    _Pragma("unroll")                                                                    \
    for (int c = 0; c < 4; ++c) {                                                        \
      int rowk = w * 8 + c * 2 + (lane >> 5);                                            \
      gload16(kg + (long)(kb_ + rowk) * QKV_COLS + (((lane & 31) ^ (rowk & 7)) * 8),     \
              &Kb[b_][w * 2048 + c * 512]);                                              \
      int rowv = w * 32 + c * 8 + (lane >> 3);                                           \
      gload16(vg + (long)rowv * SEQ + kb_ + (((lane & 7) ^ (rowv & 7)) * 8),             \
              &Vb[b_][w * 2048 + c * 512]);                                              \
    }                                                                                    \
  }

  ATTN_STAGE(t0);
  __syncthreads();
  for (int tt = t0; tt < t1; ++tt) {
    if (tt + 1 < t1) ATTN_STAGE(tt + 1);
    int b = tt & 1;
    int kb = tt * 64;
    bool active = !(kb > qhi || kb + 63 < qlo - (WINDOW - 1));
    if (active) {
      bool full = (kb + 63 <= qlo) && (qhi - kb <= WINDOW - 1);
      // ---- QK^T: one 32x32 tile (this wave's 32 keys), 16 MFMA ----
      f32x16 sc = {0.f, 0.f, 0.f, 0.f, 0.f, 0.f, 0.f, 0.f,
                   0.f, 0.f, 0.f, 0.f, 0.f, 0.f, 0.f, 0.f};
      int key = dh * 32 + l31;
      __builtin_amdgcn_s_setprio(1);
#pragma unroll
      for (int ks = 0; ks < 16; ++ks) {
        bf16x8 kf = *(const bf16x8*)&Kb[b][key * 256 + (((2 * ks + hi) ^ (lane & 7)) * 8)];
        sc = __builtin_amdgcn_mfma_f32_32x32x16_bf16(qf[ks], kf, sc, 0, 0, 0);
      }
      __builtin_amdgcn_s_setprio(0);
      // ---- softcap+softmax (D: row q=(reg&3)+8*(reg>>2)+4*hi, col key) ----
#pragma unroll
      for (int reg = 0; reg < 16; ++reg) {
        int ql = (reg & 3) + 8 * (reg >> 2) + 4 * hi;
        float s = sc[reg];
        float e = __expf(s * (2.0f * SCALE_F / CAP_F));
        float rr = __builtin_amdgcn_rcpf(e + 1.0f);
        float p = __expf(fmaf(-100.0f, rr, 38.0f));
        if (!full) {
          int q = qw + ql;
          int k = kb + key;
          p = ((k <= q) && (q - k < WINDOW)) ? p : 0.0f;
        }
        lsum16[reg] += p;
        pw[ql * 72 + key] = (bf16_t)p;
      }
    }
    // ---- wave-pair P handoff: own ds_writes done -> block barrier ----
    asm volatile("s_waitcnt lgkmcnt(0)" ::: "memory");
    __builtin_amdgcn_s_barrier();
    __builtin_amdgcn_sched_barrier(0);
    if (active) {
      // ---- PV: A = P[32q x 64k] (4 frags reused), B = V half (128 d) ----
      bf16x8 pa[4];
#pragma unroll
      for (int ks = 0; ks < 4; ++ks)
        pa[ks] = *(const bf16x8*)&pw[l31 * 72 + ks * 16 + hi * 8];
      __builtin_amdgcn_s_setprio(1);
#pragma unroll
      for (int dt = 0; dt < 4; ++dt) {
        int d = dh * 128 + dt * 32 + l31;
#pragma unroll
        for (int ks = 0; ks < 4; ++ks) {
          bf16x8 vf = *(const bf16x8*)&Vb[b][d * 64 + (((2 * ks + hi) ^ (lane & 7)) * 8)];
          acc[dt] = __builtin_amdgcn_mfma_f32_32x32x16_bf16(pa[ks], vf, acc[dt], 0, 0, 0);
        }
      }
      __builtin_amdgcn_s_setprio(0);
    }
    __syncthreads();
  }
  // ---- lsum: reduce over 32 lanes (5 shfl), exchange across wave pair ----
#pragma unroll
  for (int reg = 0; reg < 16; ++reg) {
    float s = lsum16[reg];
    s += __shfl_xor(s, 1);
    s += __shfl_xor(s, 2);
    s += __shfl_xor(s, 4);
    s += __shfl_xor(s, 8);
    s += __shfl_xor(s, 16);
    lsum16[reg] = s;
  }
  if (l31 == 0) {
#pragma unroll
    for (int reg = 0; reg < 16; ++reg)
      Ls[qg][dh][(reg & 3) + 8 * (reg >> 2) + 4 * hi] = lsum16[reg];
  }
  __syncthreads();
  // ---- normalize + write: acc[dt][reg] -> O[qw+ql][dh*128 + dt*32 + l31] ----
#pragma unroll
  for (int reg = 0; reg < 16; ++reg) {
    int ql = (reg & 3) + 8 * (reg >> 2) + 4 * hi;
    float inv = 1.0f / (lsum16[reg] + Ls[qg][1 - dh][ql]);
    long row = qw + ql;
#pragma unroll
    for (int dt = 0; dt < 4; ++dt) {
      attn_out[row * Q_SIZE + h * DH + dh * 128 + dt * 32 + l31] =
          (bf16_t)(acc[dt][reg] * inv);
    }
  }
}

extern "C" void kernel_launch(void* const* d_in, const int* in_sizes, int n_in,
                              void* d_out, int out_size, void* d_ws, size_t ws_size,
                              hipStream_t stream) {
  const float* hid_f  = (const float*)d_in[1];
  const float* wqkv_f = (const float*)d_in[2];
  const float* wo_f   = (const float*)d_in[3];
  float* out = (float*)d_out;
  char* ws = (char*)d_ws;
  bf16_t* qkv    = (bf16_t*)(ws);                 // 67,108,864
  bf16_t* wo_b   = (bf16_t*)(ws + 67108864);      // 29,360,128
  bf16_t* hid_b  = (bf16_t*)(ws + 96468992);      // 29,360,128
  bf16_t* wqkv_b = (bf16_t*)(ws + 125829120);     // 58,720,256
  bf16_t* attn_b = (bf16_t*)(ws + 96468992);      // alias over hid_b (dead after GEMM1)
  bf16_t* vt     = (bf16_t*)d_out;                // V^T scratch in d_out (read by attn
                                                  // before gemm2 overwrites d_out)

  cvt_all<<<28672, 256, 0, stream>>>(hid_f, wqkv_f, wo_f, hid_b, wqkv_b, wo_b);
  gemm_bt<HIDDEN, 1><<<512, 512, 0, stream>>>(hid_b, wqkv_b, qkv, vt, QKV_COLS);
  rope_k_kernel<<<2048, 256, 0, stream>>>(qkv);
  attn_kernel<<<512, 512, 0, stream>>>(qkv, vt, attn_b);
  gemm_bt<Q_SIZE, 0><<<224, 512, 0, stream>>>(attn_b, wo_b, out, nullptr, HIDDEN);
}

// Round 22
// 569.334 us; speedup vs baseline: 1.4015x; 1.4015x over previous
//
#include <hip/hip_runtime.h>
#include <hip/hip_bf16.h>

typedef __bf16 bf16_t;
typedef __bf16 bf16x4 __attribute__((ext_vector_type(4)));
typedef __bf16 bf16x8 __attribute__((ext_vector_type(8)));
typedef float f32x4 __attribute__((ext_vector_type(4)));

#define HIDDEN 3584
#define NQH 16
#define NKVH 8
#define DH 256
#define SEQ 4096
#define QKV_COLS 8192   // (NQH + 2*NKVH) * DH
#define Q_SIZE 4096     // NQH * DH
#define KV_SIZE 2048    // NKVH * DH
#define WINDOW 2048
#define SCALE_F 0.0625f // 256^-0.5
#define CAP_F 50.0f

__device__ __forceinline__ void gload16(const bf16_t* g, bf16_t* l) {
  __builtin_amdgcn_global_load_lds((__attribute__((address_space(1))) void*)g,
                                   (__attribute__((address_space(3))) void*)l, 16, 0, 0);
}

// ---------------- f32 -> bf16 conversion, all three inputs in one launch ----------------
__global__ __launch_bounds__(256) void cvt_all(const float* __restrict__ hid,
                                               const float* __restrict__ wqkv,
                                               const float* __restrict__ wo,
                                               bf16_t* __restrict__ hb,
                                               bf16_t* __restrict__ qb,
                                               bf16_t* __restrict__ wb) {
  long i = (long)blockIdx.x * 256 + threadIdx.x;
  const float* src;
  bf16_t* dst;
  long off;
  if (i < 1835008)       { src = hid;  dst = hb; off = i; }
  else if (i < 5505024)  { src = wqkv; dst = qb; off = i - 1835008; }
  else                   { src = wo;   dst = wb; off = i - 5505024; }
  const float4* s4 = (const float4*)src;
  float4 a = s4[off * 2];
  float4 b = s4[off * 2 + 1];
  bf16x8 o;
  o[0] = (bf16_t)a.x; o[1] = (bf16_t)a.y; o[2] = (bf16_t)a.z; o[3] = (bf16_t)a.w;
  o[4] = (bf16_t)b.x; o[5] = (bf16_t)b.y; o[6] = (bf16_t)b.z; o[7] = (bf16_t)b.w;
  *(bf16x8*)(dst + off * 8) = o;
}

// ---------------- bf16 GEMM, C[4096,N] = A[4096,K] * B[N,K]^T ----------------
// 256x256 tile, BK=32, 8 waves (2Mx4N), 4-deep LDS pipeline, counted vmcnt,
// single end-of-tile barrier (round-20).
#define TILE(T, WSTR, STAGE)                                                                \
  {                                                                                         \
    char* buf = lds + ((T) & 3) * 32768;                                                    \
    bf16x8 af[8], b0, b1, b2, b3;                                                           \
    _Pragma("unroll")                                                                       \
    for (int i = 0; i < 8; ++i) af[i] = *(const bf16x8*)(buf + aoff + i * 1024);            \
    b0 = *(const bf16x8*)(buf + boff);                                                      \
    b1 = *(const bf16x8*)(buf + boff + 1024);                                               \
    if (STAGE) {                                                                            \
      char* d = lds + (((T) + 3) & 3) * 32768;                                              \
      gload16(sA0 + ((T) + 3) * 32, (bf16_t*)(d + sdst0));                                  \
      gload16(sA1 + ((T) + 3) * 32, (bf16_t*)(d + 8192 + sdst0));                           \
    }                                                                                       \
    __builtin_amdgcn_s_setprio(1);                                                          \
    _Pragma("unroll")                                                                       \
    for (int i = 0; i < 8; ++i) {                                                           \
      acc[i][0] = __builtin_amdgcn_mfma_f32_16x16x32_bf16(af[i], b0, acc[i][0], 0, 0, 0);   \
      acc[i][1] = __builtin_amdgcn_mfma_f32_16x16x32_bf16(af[i], b1, acc[i][1], 0, 0, 0);   \
    }                                                                                       \
    __builtin_amdgcn_s_setprio(0);                                                          \
    b2 = *(const bf16x8*)(buf + boff + 2048);                                               \
    b3 = *(const bf16x8*)(buf + boff + 3072);                                               \
    if (STAGE) {                                                                            \
      char* d = lds + (((T) + 3) & 3) * 32768;                                              \
      gload16(sB0 + ((T) + 3) * 32, (bf16_t*)(d + 16384 + sdst0));                          \
      gload16(sB1 + ((T) + 3) * 32, (bf16_t*)(d + 24576 + sdst0));                          \
    }                                                                                       \
    __builtin_amdgcn_s_setprio(1);                                                          \
    _Pragma("unroll")                                                                       \
    for (int i = 0; i < 8; ++i) {                                                           \
      acc[i][2] = __builtin_amdgcn_mfma_f32_16x16x32_bf16(af[i], b2, acc[i][2], 0, 0, 0);   \
      acc[i][3] = __builtin_amdgcn_mfma_f32_16x16x32_bf16(af[i], b3, acc[i][3], 0, 0, 0);   \
    }                                                                                       \
    __builtin_amdgcn_s_setprio(0);                                                          \
    asm volatile("s_waitcnt vmcnt(" WSTR ")" ::: "memory");                                 \
    __builtin_amdgcn_s_barrier();                                                           \
  }

template <int K, int MODE>
__global__ __launch_bounds__(512, 2) void gemm_bt(const bf16_t* __restrict__ A,
                                                  const bf16_t* __restrict__ B,
                                                  void* __restrict__ Cout,
                                                  bf16_t* __restrict__ vtout, int N) {
  constexpr int NT = K / 32;
  __shared__ char lds[4 * 32768];
  int tid = threadIdx.x;
  int lane = tid & 63, w = tid >> 6;
  int wm = w >> 2, wn = w & 3;
  int r16 = lane & 15, g = lane >> 4;
  int bid = blockIdx.x;
  long bm = (long)((bid & 7) * 2 + ((bid >> 3) & 1)) * 256;
  long bn = (long)(bid >> 4) * 256;
  int ro = r16 >> 1;
  int asl = ((g + ((r16 & 1) << 2)) ^ ro) << 4;
  int aoff = wm * 8192 + ro * 128 + asl;
  int boff = 16384 + wn * 4096 + ro * 128 + asl;
  int slr = lane >> 3;
  int lc = (lane & 7) ^ slr;
  int kc8 = (lc & 3) * 8;
  long mr0 = (long)(w * 8 + slr) * 2 + (lc >> 2);
  long mr1 = mr0 + 128;
  const bf16_t* sA0 = A + (bm + mr0) * K + kc8;
  const bf16_t* sA1 = A + (bm + mr1) * K + kc8;
  const bf16_t* sB0 = B + (bn + mr0) * K + kc8;
  const bf16_t* sB1 = B + (bn + mr1) * K + kc8;
  int sdst0 = w * 1024;
  f32x4 acc[8][4] = {};
#pragma unroll
  for (int u = 0; u < 3; ++u) {
    char* d = lds + u * 32768;
    gload16(sA0 + u * 32, (bf16_t*)(d + sdst0));
    gload16(sA1 + u * 32, (bf16_t*)(d + 8192 + sdst0));
    gload16(sB0 + u * 32, (bf16_t*)(d + 16384 + sdst0));
    gload16(sB1 + u * 32, (bf16_t*)(d + 24576 + sdst0));
  }
  asm volatile("s_waitcnt vmcnt(8)" ::: "memory");
  __builtin_amdgcn_s_barrier();
  int t = 0;
  for (; t < NT - 3; ++t) TILE(t, "8", true);
  TILE(t, "4", false); ++t;
  TILE(t, "0", false); ++t;
  TILE(t, "0", false);
  if (MODE == 1 && bn >= (Q_SIZE + KV_SIZE)) {
    // fused V-transpose: vt[col_v][row], 4 consecutive rows per lane
#pragma unroll
    for (int i = 0; i < 8; ++i) {
      long row = bm + wm * 128 + i * 16 + g * 4;
#pragma unroll
      for (int j = 0; j < 4; ++j) {
        long colv = bn - (Q_SIZE + KV_SIZE) + wn * 64 + j * 16 + r16;
        bf16x4 o;
#pragma unroll
        for (int r = 0; r < 4; ++r) o[r] = (bf16_t)acc[i][j][r];
        *(bf16x4*)&vtout[colv * SEQ + row] = o;
      }
    }
  } else {
#pragma unroll
    for (int i = 0; i < 8; ++i)
#pragma unroll
      for (int j = 0; j < 4; ++j)
#pragma unroll
        for (int r = 0; r < 4; ++r) {
          long row = bm + wm * 128 + i * 16 + g * 4 + r;
          long col = bn + wn * 64 + j * 16 + r16;
          if (MODE == 1) ((bf16_t*)Cout)[row * N + col] = (bf16_t)acc[i][j][r];
          else           ((float*)Cout)[row * N + col]  = acc[i][j][r];
        }
  }
}

// ---------------- RoPE (neox) for K heads only (q roped inside attn) ----------------
__global__ __launch_bounds__(256) void rope_k_kernel(bf16_t* __restrict__ qkv) {
  long idx = (long)blockIdx.x * 256 + threadIdx.x;  // SEQ * 8 * 16 threads
  int i8 = (int)(idx & 15) * 8;
  long rem = idx >> 4;
  int head = (int)(rem & 7);
  int s = (int)(rem >> 3);
  long p1 = (long)s * QKV_COLS + Q_SIZE + head * DH + i8;
  bf16x8 x1 = *(const bf16x8*)&qkv[p1];
  bf16x8 x2 = *(const bf16x8*)&qkv[p1 + 128];
  bf16x8 o1, o2;
#pragma unroll
  for (int j = 0; j < 8; ++j) {
    float inv_freq = exp2f((float)(i8 + j) * -0.10381025296522976f);
    float fr = (float)s * inv_freq;
    float sn, cs;
    sincosf(fr, &sn, &cs);
    float a = (float)x1[j], b = (float)x2[j];
    o1[j] = (bf16_t)(a * cs - b * sn);
    o2[j] = (bf16_t)(b * cs + a * sn);
  }
  *(bf16x8*)&qkv[p1] = o1;
  *(bf16x8*)&qkv[p1 + 128] = o2;
}

// ---------------- flash attention: softcap + sliding window + GQA ----------------
// Round-14 champion structure: 128 q x 1 head, 8 waves x 16 q, 64-key tiles,
// dbuf issue-early K+V staging, in-register Q-rope, folded softmax, P LDS
// roundtrip, complementary qb pairing.
__global__ __launch_bounds__(512, 2) void attn_kernel(const bf16_t* __restrict__ qkv,
                                                      const bf16_t* __restrict__ vt,
                                                      bf16_t* __restrict__ attn_out) {
  __shared__ bf16_t Kb[2][64 * 256];   // 2 x 32 KB
  __shared__ bf16_t Vb[2][256 * 64];   // 2 x 32 KB
  __shared__ bf16_t Pl[8 * 1024];      // 16 KB, 2KB per wave, XOR-swizzled
  int tid = threadIdx.x;
  int lane = tid & 63, w = tid >> 6;
  int r16 = lane & 15, g = lane >> 4;
  int bid = blockIdx.x;
  int swz = (bid & 7) * 64 + (bid >> 3);
  int h = swz >> 5;
  int qb0 = swz & 31;
  int qb = (h & 1) ? (31 - qb0) : qb0;  // complementary pairing
  int kvh = h >> 1;
  int qw = qb * 128 + w * 16;
  bf16x8 qf[8];
  long qoff = (long)(qw + r16) * QKV_COLS + h * DH + g * 8;
#pragma unroll
  for (int kk = 0; kk < 8; ++kk) qf[kk] = *(const bf16x8*)&qkv[qoff + kk * 32];
  // ---- Q-rope in-register: pair (d, d+128) = (qf[kk][j], qf[kk+4][j]) ----
#pragma unroll
  for (int kk = 0; kk < 4; ++kk)
#pragma unroll
    for (int j = 0; j < 8; ++j) {
      int d = kk * 32 + g * 8 + j;
      float inv_freq = exp2f((float)d * -0.10381025296522976f);
      float fr = (float)(qw + r16) * inv_freq;
      float sn, cs;
      sincosf(fr, &sn, &cs);
      float a = (float)qf[kk][j], b2 = (float)qf[kk + 4][j];
      qf[kk][j] = (bf16_t)(a * cs - b2 * sn);
      qf[kk + 4][j] = (bf16_t)(b2 * cs + a * sn);
    }
  f32x4 acc[16] = {};
  float lsum[4] = {};
  const bf16_t* kg = qkv + Q_SIZE + (long)kvh * DH;
  const bf16_t* vg = vt + (long)kvh * DH * SEQ;
  bf16_t* pw = Pl + w * 1024;
  int lo = qb * 128 - (WINDOW - 1);
  int t0 = lo > 0 ? (lo >> 6) : 0;
  int t1 = qb * 2 + 2;
  int qlo = qw, qhi = qw + 15;

#define ATTN_STAGE(TT)                                                                   \
  {                                                                                      \
    int b_ = (TT) & 1;                                                                   \
    int kb_ = (TT) * 64;                                                                 \
    _Pragma("unroll")                                                                    \
    for (int c = 0; c < 4; ++c) {                                                        \
      int rowk = w * 8 + c * 2 + (lane >> 5);                                            \
      gload16(kg + (long)(kb_ + rowk) * QKV_COLS + (((lane & 31) ^ (rowk & 7)) * 8),     \
              &Kb[b_][w * 2048 + c * 512]);                                              \
      int rowv = w * 32 + c * 8 + (lane >> 3);                                           \
      gload16(vg + (long)rowv * SEQ + kb_ + (((lane & 7) ^ (rowv & 7)) * 8),             \
              &Vb[b_][w * 2048 + c * 512]);                                              \
    }                                                                                    \
  }

  ATTN_STAGE(t0);
  __syncthreads();
  for (int tt = t0; tt < t1; ++tt) {
    if (tt + 1 < t1) ATTN_STAGE(tt + 1);
    int b = tt & 1;
    int kb = tt * 64;
    bool active = !(kb > qhi || kb + 63 < qlo - (WINDOW - 1));
    if (active) {
      bool full = (kb + 63 <= qlo) && (qhi - kb <= WINDOW - 1);
      // ---- QK^T: 32 MFMA ----
      f32x4 sc[4] = {};
      __builtin_amdgcn_s_setprio(1);
#pragma unroll
      for (int kk = 0; kk < 8; ++kk) {
        int sl = ((kk * 4 + g) ^ (r16 & 7)) * 8;
#pragma unroll
        for (int c = 0; c < 4; ++c) {
          bf16x8 kf = *(const bf16x8*)&Kb[b][(c * 16 + r16) * 256 + sl];
          sc[c] = __builtin_amdgcn_mfma_f32_16x16x32_bf16(qf[kk], kf, sc[c], 0, 0, 0);
        }
      }
      __builtin_amdgcn_s_setprio(0);
      // ---- folded softcap+softmax: p = exp(38 - 100/(e+1)), e = exp(s*0.0025) ----
#pragma unroll
      for (int c = 0; c < 4; ++c)
#pragma unroll
        for (int r = 0; r < 4; ++r) {
          float s = sc[c][r];
          float e = __expf(s * (2.0f * SCALE_F / CAP_F));
          float rr = __builtin_amdgcn_rcpf(e + 1.0f);
          float p = __expf(fmaf(-100.0f, rr, 38.0f));
          if (!full) {
            int q = qw + g * 4 + r;
            int k = kb + c * 16 + r16;
            p = ((k <= q) && (q - k < WINDOW)) ? p : 0.0f;
          }
          lsum[r] += p;
          int prow = g * 4 + r;
          int pbyte = prow * 128 + ((c * 32 + r16 * 2) ^ ((prow & 7) << 4));
          *(bf16_t*)((char*)pw + pbyte) = (bf16_t)p;
        }
      // ---- P fragments (b128 reads) ----
      bf16x8 pa[2];
#pragma unroll
      for (int pk = 0; pk < 2; ++pk) {
        int pb = r16 * 128 + ((pk * 64 + g * 16) ^ ((r16 & 7) << 4));
        pa[pk] = *(const bf16x8*)((const char*)pw + pb);
      }
      // ---- PV: 32 MFMA ----
      __builtin_amdgcn_s_setprio(1);
#pragma unroll
      for (int dt = 0; dt < 16; ++dt) {
        int vrow = (dt * 16 + r16) * 64;
        bf16x8 vf0 = *(const bf16x8*)&Vb[b][vrow + ((g ^ (r16 & 7)) * 8)];
        acc[dt] = __builtin_amdgcn_mfma_f32_16x16x32_bf16(pa[0], vf0, acc[dt], 0, 0, 0);
        bf16x8 vf1 = *(const bf16x8*)&Vb[b][vrow + (((4 + g) ^ (r16 & 7)) * 8)];
        acc[dt] = __builtin_amdgcn_mfma_f32_16x16x32_bf16(pa[1], vf1, acc[dt], 0, 0, 0);
      }
      __builtin_amdgcn_s_setprio(0);
    }
    __syncthreads();
  }
  // ---- normalize + write ----
  float inv[4];
#pragma unroll
  for (int r = 0; r < 4; ++r) {
    float s = lsum[r];
    s += __shfl_xor(s, 1);
    s += __shfl_xor(s, 2);
    s += __shfl_xor(s, 4);
    s += __shfl_xor(s, 8);
    inv[r] = 1.0f / s;
  }
#pragma unroll
  for (int dt = 0; dt < 16; ++dt)
#pragma unroll
    for (int r = 0; r < 4; ++r) {
      long row = qw + g * 4 + r;
      attn_out[row * Q_SIZE + h * DH + dt * 16 + r16] = (bf16_t)(acc[dt][r] * inv[r]);
    }
}

extern "C" void kernel_launch(void* const* d_in, const int* in_sizes, int n_in,
                              void* d_out, int out_size, void* d_ws, size_t ws_size,
                              hipStream_t stream) {
  const float* hid_f  = (const float*)d_in[1];
  const float* wqkv_f = (const float*)d_in[2];
  const float* wo_f   = (const float*)d_in[3];
  float* out = (float*)d_out;
  char* ws = (char*)d_ws;
  bf16_t* qkv    = (bf16_t*)(ws);                 // 67,108,864
  bf16_t* wo_b   = (bf16_t*)(ws + 67108864);      // 29,360,128
  bf16_t* hid_b  = (bf16_t*)(ws + 96468992);      // 29,360,128
  bf16_t* wqkv_b = (bf16_t*)(ws + 125829120);     // 58,720,256
  bf16_t* attn_b = (bf16_t*)(ws + 96468992);      // alias over hid_b (dead after GEMM1)
  bf16_t* vt     = (bf16_t*)d_out;                // V^T scratch in d_out (read by attn
                                                  // before gemm2 overwrites d_out)

  cvt_all<<<28672, 256, 0, stream>>>(hid_f, wqkv_f, wo_f, hid_b, wqkv_b, wo_b);
  gemm_bt<HIDDEN, 1><<<512, 512, 0, stream>>>(hid_b, wqkv_b, qkv, vt, QKV_COLS);
  rope_k_kernel<<<2048, 256, 0, stream>>>(qkv);
  attn_kernel<<<512, 512, 0, stream>>>(qkv, vt, attn_b);
  gemm_bt<Q_SIZE, 0><<<224, 512, 0, stream>>>(attn_b, wo_b, out, nullptr, HIDDEN);
}